// Round 4
// baseline (1303.557 us; speedup 1.0000x reference)
//
#include <hip/hip_runtime.h>
#include <hip/hip_bf16.h>
#include <hip/hip_fp16.h>

// ---------------- types ----------------
typedef __attribute__((ext_vector_type(8))) short bf16x8;   // 8 bf16 (4 VGPR)
typedef __attribute__((ext_vector_type(4))) float f32x4;    // MFMA acc

static __device__ __forceinline__ unsigned short f2bf(float f) {
  unsigned u = __float_as_uint(f);
  u += 0x7fffu + ((u >> 16) & 1u);   // RNE
  return (unsigned short)(u >> 16);
}
static __device__ __forceinline__ short fb(float f) {
  union { __hip_bfloat16 b; short s; } u;
  u.b = __float2bfloat16(f);          // RNE, compiler may fuse pairs to cvt_pk
  return u.s;
}
static __device__ __forceinline__ float sigm(float x) {
  return __builtin_amdgcn_rcpf(1.0f + __expf(-x));
}
static __device__ __forceinline__ float tanh_fast(float x) {
  return 2.0f * __builtin_amdgcn_rcpf(1.0f + __expf(-2.0f * x)) - 1.0f;
}
static __device__ __forceinline__ f32x4 splat4(float g) {
  f32x4 v; v[0] = g; v[1] = g; v[2] = g; v[3] = g; return v;
}
static __device__ __forceinline__ bf16x8 pack8(float4 a, float4 b) {
  bf16x8 v;
  v[0] = fb(a.x); v[1] = fb(a.y); v[2] = fb(a.z); v[3] = fb(a.w);
  v[4] = fb(b.x); v[5] = fb(b.y); v[6] = fb(b.z); v[7] = fb(b.w);
  return v;
}

// ---------------- phase 0: weight transpose + bf16 convert ----------------
// wT layout: [set 2][n 768][k 320] bf16 ; n<512 -> gate cols (r:0-255,u:256-511), n>=512 -> cand cols
__global__ void prep_weights(const float* __restrict__ fw_gw, const float* __restrict__ fw_cw,
                             const float* __restrict__ bw_gw, const float* __restrict__ bw_cw,
                             unsigned short* __restrict__ wT) {
  int gid = blockIdx.x * 256 + threadIdx.x;   // 480*256 = 122880 threads, 4 elems each
  int kg = gid % 80;
  int n  = (gid / 80) % 768;
  int s  = gid / (80 * 768);
  if (s >= 2) return;
  const float* gw = s ? bw_gw : fw_gw;
  const float* cw = s ? bw_cw : fw_cw;
  unsigned short* dst = wT + ((size_t)s * 768 + n) * 320 + kg * 4;
  #pragma unroll
  for (int j = 0; j < 4; ++j) {
    int k = kg * 4 + j;
    float v = (n < 512) ? gw[(size_t)k * 512 + n] : cw[(size_t)k * 256 + (n - 512)];
    dst[j] = f2bf(v);
  }
}

// ---------------- phase 1: persistent dual-GRU, weights on-chip ----------------
// grid 256: ci = blockIdx>>6 in {0:tgt_fw, 1:tgt_bw, 2:prb_fw, 3:prb_bw}; rb = blockIdx&63.
// 16 batch rows per WG. Gate weights in VGPRs (wave w owns r-cols w*32..+31 and
// u-cols 256+w*32..+31 so u_pre stays in registers). Cand rh-weights in LDS
// (conflict-free linear tile layout), cand x-weights in VGPRs.
// amdgpu_waves_per_eu(2,2): 256-VGPR budget (LDS caps us at 1 WG/CU anyway) —
// without this the backend targets 4 waves/EU (128 VGPR) and spills the weights.
__global__ __attribute__((amdgpu_flat_work_group_size(512, 512), amdgpu_waves_per_eu(2, 2)))
void gru_kernel(
    const float* __restrict__ seq,
    const float* __restrict__ fw_gb, const float* __restrict__ fw_cb,
    const float* __restrict__ bw_gb, const float* __restrict__ bw_cb,
    const unsigned short* __restrict__ wT,
    float* __restrict__ h_cat) {
  __shared__ unsigned short wcLDS[256 * 256];  // cand rh-weights, linear-tile frags: 131072 B
  __shared__ unsigned short hA[16 * 256];      // bf16 h, XOR-swizzled: 8192 B
  __shared__ unsigned short rhA[16 * 256];     // bf16 r*h, XOR-swizzled: 8192 B

  const int tid  = threadIdx.x;
  const int wave = tid >> 6;
  const int lane = tid & 63;
  const int l15  = lane & 15;
  const int lk   = lane >> 4;
  const int ci   = blockIdx.x >> 6;   // chain id
  const int rb   = blockIdx.x & 63;   // row block
  const int s    = ci & 1;            // weight set: 0 fw, 1 bw
  const int tbase = (ci >> 1) * 256;  // 0 target, 256 probe

  const unsigned short* wg = wT + (size_t)s * (768 * 320);
  const unsigned short* wc = wg + (size_t)512 * 320;
  const float* gbp = s ? bw_gb : fw_gb;
  const float* cbp = s ? bw_cb : fw_cb;

  // ---- one-time: stage cand rh-weights into LDS, linear B-fragment layout ----
  // element (col = c16*16 + l15, k = 64 + kk*32 + lk*8 ..+8) stored at byte
  // (((c16*8 + kk)*4 + lk)*16 + l15)*16  -> wave reads are contiguous 1KB.
  for (int i = tid; i < 8192; i += 512) {
    const int l15s = i & 15, lks = (i >> 4) & 3, kks = (i >> 6) & 7, c16 = i >> 9;
    bf16x8 v = *(const bf16x8*)(wc + (size_t)(c16 * 16 + l15s) * 320 + 64 + kks * 32 + lks * 8);
    *(bf16x8*)((char*)wcLDS + (size_t)i * 16) = v;
  }
  // ---- one-time: zero h ----
  for (int i = tid; i < 2048; i += 512) ((int*)hA)[i] = 0;

  const int n0c = wave * 32;   // GEMM2 cand col base (also h-col base for this wave)
  // GEMM1 gate col bases: nt 0,1 -> r cols ; nt 2,3 -> u cols for the same h-cols
  int colb[4];
  colb[0] = wave * 32;       colb[1] = wave * 32 + 16;
  colb[2] = 256 + wave * 32; colb[3] = 256 + wave * 32 + 16;

  // ---- one-time: gate weights + cand x-weights into registers ----
  bf16x8 wgr[4][10];
  #pragma unroll
  for (int nt = 0; nt < 4; ++nt) {
    const unsigned short* base = wg + (size_t)(colb[nt] + l15) * 320;
    #pragma unroll
    for (int kk = 0; kk < 10; ++kk) {
      const int k = (kk < 8) ? (64 + kk * 32) : ((kk - 8) * 32);
      wgr[nt][kk] = *(const bf16x8*)(base + k + lk * 8);
    }
  }
  bf16x8 wcx[2][2];
  #pragma unroll
  for (int nt = 0; nt < 2; ++nt) {
    const unsigned short* base = wc + (size_t)(n0c + nt * 16 + l15) * 320;
    #pragma unroll
    for (int kt = 0; kt < 2; ++kt)
      wcx[nt][kt] = *(const bf16x8*)(base + kt * 32 + lk * 8);
  }

  float gbias[4], cbias[2];
  #pragma unroll
  for (int nt = 0; nt < 4; ++nt) gbias[nt] = gbp[colb[nt] + l15];
  #pragma unroll
  for (int nt = 0; nt < 2; ++nt) cbias[nt] = cbp[n0c + nt * 16 + l15];

  const float* seqrow = seq + (size_t)(rb * 16 + l15) * (512 * 64) + lk * 8;

  f32x4 hreg[2];   // persistent f32 h at this lane's GEMM2 C-frag positions
  hreg[0] = splat4(0.f); hreg[1] = splat4(0.f);

  // ---- x prefetch (one step ahead): raw f32, converted at use ----
  float4 raw[4];
  {
    const int tg0 = tbase + (s ? 255 : 0);
    const float* b = seqrow + (size_t)tg0 * 64;
    raw[0] = *(const float4*)(b);      raw[1] = *(const float4*)(b + 4);
    raw[2] = *(const float4*)(b + 32); raw[3] = *(const float4*)(b + 36);
  }

  __syncthreads();

  #pragma unroll 1
  for (int t = 0; t < 256; ++t) {
    // ---- convert current x, then issue next-step loads (hidden under GEMMs) ----
    bf16x8 xf[2];
    xf[0] = pack8(raw[0], raw[1]);
    xf[1] = pack8(raw[2], raw[3]);
    {
      const int tn  = (t < 255) ? (t + 1) : 255;
      const int tgn = tbase + (s ? (255 - tn) : tn);
      const float* b = seqrow + (size_t)tgn * 64;
      raw[0] = *(const float4*)(b);      raw[1] = *(const float4*)(b + 4);
      raw[2] = *(const float4*)(b + 32); raw[3] = *(const float4*)(b + 36);
    }

    // ---- GEMM1: ru_pre = [h|x] @ gw + gb ----
    f32x4 acc1[4];
    #pragma unroll
    for (int nt = 0; nt < 4; ++nt) acc1[nt] = splat4(gbias[nt]);
    #pragma unroll
    for (int kk = 0; kk < 10; ++kk) {
      bf16x8 a0;
      if (kk < 8) {
        const int byte0 = (l15 * 512 + (kk * 32 + lk * 8) * 2) ^ ((l15 & 7) << 4);
        a0 = *(const bf16x8*)((const char*)hA + byte0);
      } else {
        a0 = xf[kk - 8];
      }
      #pragma unroll
      for (int nt = 0; nt < 4; ++nt)
        acc1[nt] = __builtin_amdgcn_mfma_f32_16x16x32_bf16(a0, wgr[nt][kk], acc1[nt], 0, 0, 0);
    }

    // ---- pointwise: r*h -> rhA (LDS, h from f32 regs) ; u -> registers ----
    float ur[2][4];
    #pragma unroll
    for (int nt = 0; nt < 2; ++nt)
      #pragma unroll
      for (int i = 0; i < 4; ++i) {
        const int row = lk * 4 + i;
        const int col = colb[nt] + l15;               // r col (= h col)
        const float r = sigm(acc1[nt][i]);
        const int hb = (row * 512 + col * 2) ^ ((row & 7) << 4);
        *(unsigned short*)((char*)rhA + hb) = (unsigned short)fb(r * hreg[nt][i]);
        ur[nt][i] = sigm(acc1[nt + 2][i]);            // u for same (row,col)
      }
    __syncthreads();

    // ---- GEMM2: c_pre = [rh|x] @ cw + cb ----
    f32x4 acc2[2];
    #pragma unroll
    for (int nt = 0; nt < 2; ++nt) acc2[nt] = splat4(cbias[nt]);
    #pragma unroll
    for (int kk = 0; kk < 10; ++kk) {
      bf16x8 a0;
      if (kk < 8) {
        const int byte0 = (l15 * 512 + (kk * 32 + lk * 8) * 2) ^ ((l15 & 7) << 4);
        a0 = *(const bf16x8*)((const char*)rhA + byte0);
      } else {
        a0 = xf[kk - 8];
      }
      #pragma unroll
      for (int nt = 0; nt < 2; ++nt) {
        bf16x8 b;
        if (kk < 8) {
          const int c16 = wave * 2 + nt;
          b = *(const bf16x8*)((const char*)wcLDS +
                (size_t)((((c16 * 8 + kk) * 4 + lk) * 16 + l15) * 16));
        } else {
          b = wcx[nt][kk - 8];
        }
        acc2[nt] = __builtin_amdgcn_mfma_f32_16x16x32_bf16(a0, b, acc2[nt], 0, 0, 0);
      }
    }

    // ---- update: h = u*h + (1-u)*tanh(c_pre) ; h kept f32 in regs ----
    const bool last = (t == 255);
    #pragma unroll
    for (int nt = 0; nt < 2; ++nt)
      #pragma unroll
      for (int i = 0; i < 4; ++i) {
        const int row = lk * 4 + i;
        const int col = n0c + nt * 16 + l15;
        const float cv = tanh_fast(acc2[nt][i]);
        const float u = ur[nt][i];
        const float hn = u * hreg[nt][i] + (1.f - u) * cv;
        hreg[nt][i] = hn;
        const int hb = (row * 512 + col * 2) ^ ((row & 7) << 4);
        *(unsigned short*)((char*)hA + hb) = (unsigned short)fb(hn);
        if (last) {
          h_cat[(size_t)(rb * 16 + row) * 1024 + ci * 256 + col] = hn;
        }
      }
    __syncthreads();
  }
}

// ---------------- phase 2: MLP (all f32 for accuracy; cheap) ----------------
__global__ __launch_bounds__(256) void mlp1(const float* __restrict__ h_cat,
                                            const float* __restrict__ gf,
                                            const float* __restrict__ w1,
                                            const float* __restrict__ b1,
                                            float* __restrict__ a1) {
  __shared__ float xs[8][1036];
  const int tid = threadIdx.x;
  const int r0 = blockIdx.x * 8;
  for (int i = tid; i < 8 * 1032; i += 256) {
    int m = i / 1032, k = i - m * 1032;
    xs[m][k] = (k < 1024) ? h_cat[(size_t)(r0 + m) * 1024 + k]
                          : gf[(size_t)(r0 + m) * 8 + (k - 1024)];
  }
  __syncthreads();
  float acc0[8], acc1v[8];
  #pragma unroll
  for (int m = 0; m < 8; ++m) { acc0[m] = 0.f; acc1v[m] = 0.f; }
  const int n = tid;
  for (int k = 0; k < 1032; k += 4) {
    float wa[4], wb[4];
    #pragma unroll
    for (int j = 0; j < 4; ++j) {
      wa[j] = w1[(size_t)(k + j) * 512 + n];
      wb[j] = w1[(size_t)(k + j) * 512 + n + 256];
    }
    #pragma unroll
    for (int m = 0; m < 8; ++m) {
      float4 xv = *(const float4*)&xs[m][k];
      acc0[m]  = fmaf(xv.w, wa[3], fmaf(xv.z, wa[2], fmaf(xv.y, wa[1], fmaf(xv.x, wa[0], acc0[m]))));
      acc1v[m] = fmaf(xv.w, wb[3], fmaf(xv.z, wb[2], fmaf(xv.y, wb[1], fmaf(xv.x, wb[0], acc1v[m]))));
    }
  }
  const float bb0 = b1[n], bb1 = b1[n + 256];
  #pragma unroll
  for (int m = 0; m < 8; ++m) {
    a1[(size_t)(r0 + m) * 512 + n]       = fmaxf(acc0[m] + bb0, 0.f);
    a1[(size_t)(r0 + m) * 512 + n + 256] = fmaxf(acc1v[m] + bb1, 0.f);
  }
}

__global__ __launch_bounds__(256) void mlp2(const float* __restrict__ a1,
                                            const float* __restrict__ w2,
                                            const float* __restrict__ b2,
                                            float* __restrict__ a2) {
  __shared__ float xs[8][516];
  const int tid = threadIdx.x;
  const int r0 = blockIdx.x * 8;
  for (int i = tid; i < 8 * 512; i += 256) {
    int m = i >> 9, k = i & 511;
    xs[m][k] = a1[(size_t)(r0 + m) * 512 + k];
  }
  __syncthreads();
  float acc[8];
  #pragma unroll
  for (int m = 0; m < 8; ++m) acc[m] = 0.f;
  for (int k = 0; k < 512; k += 4) {
    float wa[4];
    #pragma unroll
    for (int j = 0; j < 4; ++j) wa[j] = w2[(size_t)(k + j) * 256 + tid];
    #pragma unroll
    for (int m = 0; m < 8; ++m) {
      float4 xv = *(const float4*)&xs[m][k];
      acc[m] = fmaf(xv.w, wa[3], fmaf(xv.z, wa[2], fmaf(xv.y, wa[1], fmaf(xv.x, wa[0], acc[m]))));
    }
  }
  const float bb = b2[tid];
  #pragma unroll
  for (int m = 0; m < 8; ++m)
    a2[(size_t)(r0 + m) * 256 + tid] = fmaxf(acc[m] + bb, 0.f);
}

__global__ __launch_bounds__(256) void mlp3(const float* __restrict__ a2,
                                            const float* __restrict__ w3,
                                            const float* __restrict__ b3,
                                            float* __restrict__ out) {
  const int r = blockIdx.x * 256 + threadIdx.x;
  float m = 0.f, p = 0.f;
  for (int k = 0; k < 256; k += 4) {
    float4 v = *(const float4*)&a2[(size_t)r * 256 + k];
    m = fmaf(v.x, w3[2 * k],     fmaf(v.y, w3[2 * k + 2], fmaf(v.z, w3[2 * k + 4], fmaf(v.w, w3[2 * k + 6], m))));
    p = fmaf(v.x, w3[2 * k + 1], fmaf(v.y, w3[2 * k + 3], fmaf(v.z, w3[2 * k + 5], fmaf(v.w, w3[2 * k + 7], p))));
  }
  out[2 * r]     = m + b3[0];
  out[2 * r + 1] = fabsf(p + b3[1]);
}

// ---------------- launch ----------------
extern "C" void kernel_launch(void* const* d_in, const int* in_sizes, int n_in,
                              void* d_out, int out_size, void* d_ws, size_t ws_size,
                              hipStream_t stream) {
  const float* seq   = (const float*)d_in[0];
  const float* gf    = (const float*)d_in[1];
  const float* fw_gw = (const float*)d_in[2];
  const float* fw_gb = (const float*)d_in[3];
  const float* fw_cw = (const float*)d_in[4];
  const float* fw_cb = (const float*)d_in[5];
  const float* bw_gw = (const float*)d_in[6];
  const float* bw_gb = (const float*)d_in[7];
  const float* bw_cw = (const float*)d_in[8];
  const float* bw_cb = (const float*)d_in[9];
  const float* w1 = (const float*)d_in[10];
  const float* b1 = (const float*)d_in[11];
  const float* w2 = (const float*)d_in[12];
  const float* b2 = (const float*)d_in[13];
  const float* w3 = (const float*)d_in[14];
  const float* b3 = (const float*)d_in[15];
  float* out = (float*)d_out;

  char* ws = (char*)d_ws;
  unsigned short* wT = (unsigned short*)(ws);                       // 983,040 B
  float* h_cat = (float*)(ws + 983040);                             // 4 MiB
  float* a1    = (float*)(ws + 983040 + 4194304);                   // 2 MiB
  float* a2    = (float*)(ws + 983040 + 4194304 + 2097152);         // 1 MiB

  hipLaunchKernelGGL(prep_weights, dim3(480), dim3(256), 0, stream,
                     fw_gw, fw_cw, bw_gw, bw_cw, wT);
  hipLaunchKernelGGL(gru_kernel, dim3(256), dim3(512), 0, stream,
                     seq, fw_gb, fw_cb, bw_gb, bw_cb, wT, h_cat);
  hipLaunchKernelGGL(mlp1, dim3(128), dim3(256), 0, stream, h_cat, gf, w1, b1, a1);
  hipLaunchKernelGGL(mlp2, dim3(128), dim3(256), 0, stream, a1, w2, b2, a2);
  hipLaunchKernelGGL(mlp3, dim3(4), dim3(256), 0, stream, a2, w3, b3, out);
}